// Round 20
// baseline (749.616 us; speedup 1.0000x reference)
//
#include <hip/hip_runtime.h>
#include <hip/hip_fp16.h>
#include <cstdint>
#include <cstddef>

#define NODE 64
#define EDGEF 32
#define UPF 160   // 2*NODE + EDGEF
#define RD 256
#define UT_STRIDE 162  // 160 padded: float2 reads -> 2-way bank aliasing (free)

typedef unsigned int uint4n __attribute__((ext_vector_type(4)));  // native vec for nt-store

__device__ __forceinline__ float eluf(float x) { return x > 0.f ? x : expm1f(x); }

union U32H2 { unsigned int u; __half2 h; };
union H16U { __half h; unsigned short u; };

__device__ __forceinline__ float2 h2f(unsigned int u) {
    U32H2 t; t.u = u;
    return __half22float2(t.h);
}
__device__ __forceinline__ unsigned short f2h(float f) {
    H16U t; t.h = __float2half_rn(f);
    return t.u;
}

// ---------------------------------------------------------------------------
// CSR build. k_count also records each edge's rank within its dst segment
// (the atomic's return value) so the fill pass needs NO second atomic.
__global__ void k_count(const int* __restrict__ dst, int* cnt, int* rank, int E) {
    int e = blockIdx.x * 256 + threadIdx.x;
    if (e < E) rank[e] = atomicAdd(&cnt[dst[e]], 1);
}

__global__ void k_scanA(const int* __restrict__ cnt, int* starts, int* bsum, int N) {
    __shared__ int sh[256];
    int t = threadIdx.x;
    int base = blockIdx.x * 1024 + t * 4;
    int v0 = 0, v1 = 0, v2 = 0, v3 = 0;
    if (base + 0 < N) v0 = cnt[base + 0];
    if (base + 1 < N) v1 = cnt[base + 1];
    if (base + 2 < N) v2 = cnt[base + 2];
    if (base + 3 < N) v3 = cnt[base + 3];
    int tot = v0 + v1 + v2 + v3;
    sh[t] = tot;
    __syncthreads();
    for (int off = 1; off < 256; off <<= 1) {
        int add = (t >= off) ? sh[t - off] : 0;
        __syncthreads();
        sh[t] += add;
        __syncthreads();
    }
    int excl = sh[t] - tot;
    if (base + 0 < N) starts[base + 0] = excl;
    if (base + 1 < N) starts[base + 1] = excl + v0;
    if (base + 2 < N) starts[base + 2] = excl + v0 + v1;
    if (base + 3 < N) starts[base + 3] = excl + v0 + v1 + v2;
    if (t == 255) bsum[blockIdx.x] = sh[255];
}

__global__ void k_scanB(const int* __restrict__ bsum, int* boff, int nb, int* starts, int N) {
    if (threadIdx.x == 0 && blockIdx.x == 0) {
        int run = 0;
        for (int b = 0; b < nb; ++b) { boff[b] = run; run += bsum[b]; }
        starts[N] = run;
    }
}

__global__ void k_scanC(const int* __restrict__ boff, int* starts, int N) {
    int i = blockIdx.x * 256 + threadIdx.x;
    if (i < N) starts[i] += boff[i >> 10];
}

// ---------------------------------------------------------------------------
// Tiny id-scatter: pos = starts[dst] + rank; one 16B nontemporal store.
__global__ void k_fill_ids(const int* __restrict__ src, const int* __restrict__ dst,
                           const float* __restrict__ wb, const int* __restrict__ rank,
                           const int* __restrict__ starts, uint4n* __restrict__ ecsr, int E) {
    int e = blockIdx.x * 256 + threadIdx.x;
    if (e >= E) return;
    int pos = starts[dst[e]] + rank[e];
    uint4n rec;
    rec.x = (unsigned int)src[e];
    rec.y = __float_as_uint(wb[e]);
    rec.z = (unsigned int)e;
    rec.w = 0u;
    __builtin_nontemporal_store(rec, &ecsr[pos]);
}

// ---------------------------------------------------------------------------
// Edge FFN, 8-lane-group per edge (register-light; round-17: FETCH 310->52MB,
// round-18: NO min-waves bound or it spills).
__global__ __launch_bounds__(256) void k_medge(
    const float* __restrict__ ea, const float* __restrict__ wb,
    const float* __restrict__ EW, const float* __restrict__ Eb,
    unsigned short* __restrict__ medge, int E) {
    __shared__ float ew_s[EDGEF * EDGEF];
    __shared__ float eb_s[EDGEF];
    int tid = threadIdx.x;
    for (int i = tid; i < EDGEF * EDGEF; i += 256) ew_s[i] = EW[i];
    if (tid < EDGEF) eb_s[tid] = Eb[tid];
    __syncthreads();
    int lane = tid & 63, wid = tid >> 6;
    int grp = lane >> 3, gl = lane & 7;
    const float4* ea4 = (const float4*)ea;
    float4 eb4 = *(const float4*)&eb_s[gl * 4];
    for (int e0 = blockIdx.x * 32; e0 < E; e0 += gridDim.x * 32) {
        int e = e0 + wid * 8 + grp;
        float4 a4 = {0.f, 0.f, 0.f, 0.f};
        float w = 0.f;
        if (e < E) {
            a4 = ea4[(size_t)e * 8 + gl];
            w = wb[e];
        }
        float4 m = eb4;
#pragma unroll
        for (int k = 0; k < EDGEF; ++k) {
            float av;
            switch (k & 3) {
                case 0: av = a4.x; break;
                case 1: av = a4.y; break;
                case 2: av = a4.z; break;
                default: av = a4.w; break;
            }
            float ak = __shfl(av, (lane & 56) | (k >> 2), 64);
            float4 w4 = *(const float4*)&ew_s[k * EDGEF + gl * 4];
            m.x = fmaf(ak, w4.x, m.x);
            m.y = fmaf(ak, w4.y, m.y);
            m.z = fmaf(ak, w4.z, m.z);
            m.w = fmaf(ak, w4.w, m.w);
        }
        if (e < E) {
            uint2 o;
            o.x = (unsigned int)f2h(w * fmaxf(m.x, 0.f)) |
                  ((unsigned int)f2h(w * fmaxf(m.y, 0.f)) << 16);
            o.y = (unsigned int)f2h(w * fmaxf(m.z, 0.f)) |
                  ((unsigned int)f2h(w * fmaxf(m.w, 0.f)) << 16);
            *(uint2*)(medge + (size_t)e * EDGEF + gl * 4) = o;
        }
    }
}

// ---------------------------------------------------------------------------
// Segment-sum via gather: aggrE[n] = elu( sum_i medge[ecsr[i].z] ).
__global__ __launch_bounds__(256) void k_sumE(
    const unsigned short* __restrict__ medge, const uint4n* __restrict__ ecsr,
    const int* __restrict__ starts, float* __restrict__ aggrE_elu, int N) {
    int tid = threadIdx.x;
    int lane = tid & 63, wid = tid >> 6;
    int grp = lane >> 2, gl = lane & 3;      // 16 groups x 4 lanes
    int nwaves = gridDim.x * 4;
    for (int n = blockIdx.x * 4 + wid; n < N; n += nwaves) {
        int s0 = starts[n], s1 = starts[n + 1];
        float acc[8] = {0.f, 0.f, 0.f, 0.f, 0.f, 0.f, 0.f, 0.f};
        int i = s0 + grp;
        uint4 r0 = {0u,0u,0u,0u}, r1 = {0u,0u,0u,0u};
        if (i < s1)      r0 = *(const uint4*)(medge + (size_t)ecsr[i].z      * EDGEF + gl * 8);
        if (i + 16 < s1) r1 = *(const uint4*)(medge + (size_t)ecsr[i + 16].z * EDGEF + gl * 8);
        for (; i < s1; i += 16) {
            uint4 rN = {0u,0u,0u,0u};
            if (i + 32 < s1) rN = *(const uint4*)(medge + (size_t)ecsr[i + 32].z * EDGEF + gl * 8);
            float2 f0 = h2f(r0.x), f1 = h2f(r0.y), f2 = h2f(r0.z), f3 = h2f(r0.w);
            acc[0] += f0.x; acc[1] += f0.y;
            acc[2] += f1.x; acc[3] += f1.y;
            acc[4] += f2.x; acc[5] += f2.y;
            acc[6] += f3.x; acc[7] += f3.y;
            r0 = r1; r1 = rN;
        }
#pragma unroll
        for (int m2 = 4; m2 <= 32; m2 <<= 1) {
#pragma unroll
            for (int j = 0; j < 8; ++j) acc[j] += __shfl_xor(acc[j], m2, 64);
        }
        if (lane < 4) {
            float4 o0 = { eluf(acc[0]), eluf(acc[1]), eluf(acc[2]), eluf(acc[3]) };
            float4 o1 = { eluf(acc[4]), eluf(acc[5]), eluf(acc[6]), eluf(acc[7]) };
            float4* op = (float4*)(aggrE_elu + (size_t)n * EDGEF + gl * 8);
            op[0] = o0;
            op[1] = o1;
        }
    }
}

// ---------------------------------------------------------------------------
// hv = relu((ha [+ hb]) @ V_W + V_b), stored as fp16 (halves gather bytes).
__global__ __launch_bounds__(256) void k_hv(
    const float* __restrict__ ha, const float* __restrict__ hb, int addB,
    const float* __restrict__ VW, const float* __restrict__ Vb,
    unsigned short* __restrict__ hvh, int N, int chunk) {
    __shared__ float slot[4][NODE];
    int tid = threadIdx.x;
    int lane = tid & 63, w = tid >> 6;
    float vcol[NODE];
#pragma unroll
    for (int k = 0; k < NODE; ++k) vcol[k] = VW[k * NODE + lane];
    float vb = Vb[lane];
    const float4* s4 = (const float4*)slot[w];
    int n0 = blockIdx.x * chunk;
    int n1 = n0 + chunk; if (n1 > N) n1 = N;
    for (int n = n0 + w; n < n1; n += 4) {
        float hrow = ha[(size_t)n * NODE + lane];
        if (addB) hrow += hb[(size_t)n * NODE + lane];
        slot[w][lane] = hrow;
        float d0 = 0.f, d1 = 0.f, d2 = 0.f, d3 = 0.f;
#pragma unroll
        for (int q = 0; q < 16; ++q) {
            float4 h4 = s4[q];
            d0 = fmaf(h4.x, vcol[4*q+0], d0);
            d1 = fmaf(h4.y, vcol[4*q+1], d1);
            d2 = fmaf(h4.z, vcol[4*q+2], d2);
            d3 = fmaf(h4.w, vcol[4*q+3], d3);
        }
        hvh[(size_t)n * NODE + lane] = f2h(fmaxf(vb + ((d0 + d1) + (d2 + d3)), 0.f));
    }
}

// ---------------------------------------------------------------------------
// FUSED gather + node update: aggr row stays in registers/LDS, no global
// round-trip (saves 25.6MB/depth + a launch). Wave per node: gather phase
// (8-lane groups, fp16 rows, 16 rows in flight) -> shfl reduce -> lanes 0-7
// write elu'd row to per-wave myup -> U-FFN epilogue (U^T tile in LDS).
__global__ __launch_bounds__(512) void k_gupdate(
    const float* __restrict__ ha, const float* __restrict__ hb, int addB,
    const unsigned short* __restrict__ hvh,
    const int* __restrict__ starts, const uint4n* __restrict__ ecsr,
    const float* __restrict__ aggrE_elu,
    const float* __restrict__ UW, const float* __restrict__ Ub,
    const float* __restrict__ watoms, float* __restrict__ h_out, int N) {
    __shared__ float lds_Ut[NODE * UT_STRIDE];   // 41.4 KB
    __shared__ float lds_up[8 * UPF];            // 5 KB
    int tid = threadIdx.x;
    for (int idx = tid; idx < UPF * NODE; idx += 512) {
        int j = idx & 63, t2 = idx >> 6;
        lds_Ut[j * UT_STRIDE + t2] = UW[idx];
    }
    int lane = tid & 63, wid = tid >> 6;
    int grp = lane >> 3, gl = lane & 7;      // 8 groups x 8 lanes (gather phase)
    float ub = Ub[lane];
    __syncthreads();
    float* myup = lds_up + wid * UPF;
    int nwaves = gridDim.x * 8;
    for (int n = blockIdx.x * 8 + wid; n < N; n += nwaves) {
        int s0 = starts[n], s1 = starts[n + 1];
        int deg = s1 - s0;
        // ---- gather phase ----
        float acc[8] = {0.f, 0.f, 0.f, 0.f, 0.f, 0.f, 0.f, 0.f};
        uint4 r0 = {0u,0u,0u,0u}, r1 = {0u,0u,0u,0u};
        float w0 = 0.f, w1 = 0.f;
        if (grp < deg) {
            uint4n c = ecsr[s0 + grp];
            r0 = *(const uint4*)(hvh + (size_t)c.x * NODE + gl * 8);
            w0 = __uint_as_float(c.y);
        }
        if (grp + 8 < deg) {
            uint4n c = ecsr[s0 + grp + 8];
            r1 = *(const uint4*)(hvh + (size_t)c.x * NODE + gl * 8);
            w1 = __uint_as_float(c.y);
        }
        for (int i = grp; i < deg; i += 8) {
            uint4 rN = {0u,0u,0u,0u}; float wN = 0.f;
            if (i + 16 < deg) {
                uint4n c = ecsr[s0 + i + 16];
                rN = *(const uint4*)(hvh + (size_t)c.x * NODE + gl * 8);
                wN = __uint_as_float(c.y);
            }
            float2 f0 = h2f(r0.x), f1 = h2f(r0.y), f2 = h2f(r0.z), f3 = h2f(r0.w);
            acc[0] = fmaf(w0, f0.x, acc[0]);
            acc[1] = fmaf(w0, f0.y, acc[1]);
            acc[2] = fmaf(w0, f1.x, acc[2]);
            acc[3] = fmaf(w0, f1.y, acc[3]);
            acc[4] = fmaf(w0, f2.x, acc[4]);
            acc[5] = fmaf(w0, f2.y, acc[5]);
            acc[6] = fmaf(w0, f3.x, acc[6]);
            acc[7] = fmaf(w0, f3.y, acc[7]);
            r0 = r1; w0 = w1;
            r1 = rN; w1 = wN;
        }
#pragma unroll
        for (int m2 = 8; m2 <= 32; m2 <<= 1) {
#pragma unroll
            for (int j = 0; j < 8; ++j) acc[j] += __shfl_xor(acc[j], m2, 64);
        }
        // ---- splice: lane gl<8 holds channels gl*8..gl*8+7 ----
        if (lane < 8) {
#pragma unroll
            for (int j = 0; j < 8; ++j) myup[gl * 8 + j] = eluf(acc[j]);
        }
        if (lane < EDGEF) myup[NODE + lane] = aggrE_elu[(size_t)n * EDGEF + lane];
        float hrow = ha[(size_t)n * NODE + lane];
        if (addB) hrow += hb[(size_t)n * NODE + lane];
        myup[NODE + EDGEF + lane] = eluf(hrow);
        // ---- U-FFN epilogue ----
        float o = ub;
#pragma unroll
        for (int t2 = 0; t2 < UPF; t2 += 2) {
            float2 u2 = *(const float2*)&myup[t2];                 // broadcast
            float2 w2 = *(const float2*)&lds_Ut[lane * UT_STRIDE + t2];
            o = fmaf(u2.x, w2.x, o);
            o = fmaf(u2.y, w2.y, o);
        }
        h_out[(size_t)n * NODE + lane] = fmaxf(o, 0.f) * watoms[n];
    }
}

// ---------------------------------------------------------------------------
// Readout GEMM y = (ha+hb) @ R_W + R_b, fused BN column stats.
// 512 blocks (measured best: 512->71us, 2048->78us, round-19).
__global__ __launch_bounds__(256) void k_y(
    const float* __restrict__ ha, const float* __restrict__ hb,
    const float* __restrict__ RW, const float* __restrict__ Rb,
    float* __restrict__ y, float* colsum, float* colsumsq, int N, int chunk) {
    __shared__ float slot[4][NODE];
    int tid = threadIdx.x;
    int lane = tid & 63, w = tid >> 6;
    float rcol[NODE];
#pragma unroll
    for (int k = 0; k < NODE; ++k) rcol[k] = RW[k * RD + w * 64 + lane];
    float rb = Rb[w * 64 + lane];
    const float4* s4 = (const float4*)slot[w];
    float sum = 0.f, sq = 0.f;
    int n0 = blockIdx.x * chunk;
    int n1 = n0 + chunk; if (n1 > N) n1 = N;
    for (int n = n0; n < n1; ++n) {
        float hvC = ha[(size_t)n * NODE + lane] + hb[(size_t)n * NODE + lane];
        slot[w][lane] = hvC;
        float d0 = 0.f, d1 = 0.f, d2 = 0.f, d3 = 0.f;
#pragma unroll
        for (int q = 0; q < 16; ++q) {
            float4 h4 = s4[q];
            d0 = fmaf(h4.x, rcol[4*q+0], d0);
            d1 = fmaf(h4.y, rcol[4*q+1], d1);
            d2 = fmaf(h4.z, rcol[4*q+2], d2);
            d3 = fmaf(h4.w, rcol[4*q+3], d3);
        }
        float v = rb + ((d0 + d1) + (d2 + d3));
        y[(size_t)n * RD + w * 64 + lane] = v;
        sum += v; sq = fmaf(v, v, sq);
    }
    atomicAdd(&colsum[w * 64 + lane], sum);
    atomicAdd(&colsumsq[w * 64 + lane], sq);
}

// graph boundaries from sorted batch: gstart[g] = first n with batch[n] >= g
__global__ void k_gbounds(const int* __restrict__ batch, int* gstart, int N, int G) {
    int n = blockIdx.x * 256 + threadIdx.x;
    if (n > N) return;
    int bprev = (n == 0) ? -1 : batch[n - 1];
    int bcur = (n == N) ? G : batch[n];
    for (int g = bprev + 1; g <= bcur; ++g) gstart[g] = n;
}

// BN(normalize) + relu + segment mean. block per graph, thread per channel.
__global__ void k_out(const float* __restrict__ y, const float* __restrict__ colsum,
                      const float* __restrict__ colsumsq, const float* __restrict__ gamma,
                      const float* __restrict__ beta, const int* __restrict__ gstart,
                      float* __restrict__ out, float invN) {
    int g = blockIdx.x, c = threadIdx.x;
    float mu = colsum[c] * invN;
    float var = fmaxf(colsumsq[c] * invN - mu * mu, 0.f);
    float inv = rsqrtf(var + 1e-5f);
    float ga = gamma[c], be = beta[c];
    int a = gstart[g], b = gstart[g + 1];
    float acc = 0.f;
    for (int n = a; n < b; ++n) {
        float v = y[(size_t)n * RD + c];
        acc += fmaxf(fmaf((v - mu) * inv, ga, be), 0.f);
    }
    out[(size_t)g * RD + c] = acc / fmaxf((float)(b - a), 1.f);
}

// ---------------------------------------------------------------------------
extern "C" void kernel_launch(void* const* d_in, const int* in_sizes, int n_in,
                              void* d_out, int out_size, void* d_ws, size_t ws_size,
                              hipStream_t stream) {
    const float* x      = (const float*)d_in[0];
    const int*   ei     = (const int*)d_in[1];
    const float* eattr  = (const float*)d_in[2];
    const float* watoms = (const float*)d_in[3];
    const float* wbonds = (const float*)d_in[4];
    const int*   batch  = (const int*)d_in[5];
    const float* VW = (const float*)d_in[6];
    const float* Vb = (const float*)d_in[7];
    const float* EW = (const float*)d_in[8];
    const float* Eb = (const float*)d_in[9];
    const float* UW = (const float*)d_in[10];
    const float* Ub = (const float*)d_in[11];
    const float* RW = (const float*)d_in[12];
    const float* Rb = (const float*)d_in[13];
    const float* Rg = (const float*)d_in[14];
    const float* Rbe = (const float*)d_in[15];
    float* out = (float*)d_out;

    const int N = in_sizes[0] / NODE;
    const int E = in_sizes[4];
    const int G = out_size / RD;
    const int* src = ei;
    const int* dst = ei + E;

    char* p = (char*)d_ws;
    auto alloc = [&](size_t bytes) -> char* {
        char* r = p;
        p += (bytes + 255) & ~(size_t)255;
        return r;
    };
    float* aggrE   = (float*)alloc((size_t)N * EDGEF * 4);   // stores elu(aggrE)
    int*   cnt     = (int*)alloc((size_t)N * 4);
    int*   starts  = (int*)alloc((size_t)(N + 1) * 4);
    int*   rank    = (int*)alloc((size_t)E * 4);
    int*   bsum    = (int*)alloc(64 * 4);
    int*   boff    = (int*)alloc(64 * 4);
    uint4n* ecsr   = (uint4n*)alloc((size_t)E * 16);         // (src, w, e, 0) per CSR slot
    float* hA      = (float*)alloc((size_t)N * NODE * 4);    // h1, then h3 (in place)
    float* hB      = (float*)alloc((size_t)N * NODE * 4);    // h2, then h4 (in place)
    unsigned short* hvh = (unsigned short*)alloc((size_t)N * NODE * 2); // fp16 relu(V h)
    float* colstat = (float*)alloc((size_t)2 * RD * 4);
    int*   gstart  = (int*)alloc((size_t)(G + 1) * 4);
    // medge (E*32 fp16 = 51.2MB) and ybuf (N*256 f32 = 51.2MB): disjoint
    // lifetimes -> overlay.
    size_t mbytes = (size_t)E * EDGEF * 2;
    size_t ybytes = (size_t)N * RD * 4;
    float* ybuf = (float*)alloc(mbytes > ybytes ? mbytes : ybytes);
    unsigned short* medge = (unsigned short*)ybuf;

    hipMemsetAsync(cnt, 0, (size_t)N * 4, stream);
    hipMemsetAsync(colstat, 0, (size_t)2 * RD * 4, stream);

    int eblocks = (E + 255) / 256;
    int sblocks = (N + 1023) / 1024;

    k_count<<<eblocks, 256, 0, stream>>>(dst, cnt, rank, E);
    k_scanA<<<sblocks, 256, 0, stream>>>(cnt, starts, bsum, N);
    k_scanB<<<1, 64, 0, stream>>>(bsum, boff, sblocks, starts, N);
    k_scanC<<<(N + 255) / 256, 256, 0, stream>>>(boff, starts, N);
    k_fill_ids<<<eblocks, 256, 0, stream>>>(src, dst, wbonds, rank, starts, ecsr, E);
    k_medge<<<2048, 256, 0, stream>>>(eattr, wbonds, EW, Eb, medge, E);
    k_sumE<<<2048, 256, 0, stream>>>(medge, ecsr, starts, aggrE, N);

    int hvblocks = 512;
    int chunk = (N + hvblocks - 1) / hvblocks;

    // depth 0: h1 = mp(x)
    k_hv<<<hvblocks, 256, 0, stream>>>(x, x, 0, VW, Vb, hvh, N, chunk);
    k_gupdate<<<768, 512, 0, stream>>>(x, x, 0, hvh, starts, ecsr, aggrE, UW, Ub, watoms, hA, N);
    // depth 1: h2 = mp(h1)
    k_hv<<<hvblocks, 256, 0, stream>>>(hA, hA, 0, VW, Vb, hvh, N, chunk);
    k_gupdate<<<768, 512, 0, stream>>>(hA, hA, 0, hvh, starts, ecsr, aggrE, UW, Ub, watoms, hB, N);
    // depth 2: h3 = mp(h1 + h2)   (in place into hA)
    k_hv<<<hvblocks, 256, 0, stream>>>(hA, hB, 1, VW, Vb, hvh, N, chunk);
    k_gupdate<<<768, 512, 0, stream>>>(hA, hB, 1, hvh, starts, ecsr, aggrE, UW, Ub, watoms, hA, N);
    // depth 3: h4 = mp(h2 + h3)   (in place into hB)
    k_hv<<<hvblocks, 256, 0, stream>>>(hB, hA, 1, VW, Vb, hvh, N, chunk);
    k_gupdate<<<768, 512, 0, stream>>>(hB, hA, 1, hvh, starts, ecsr, aggrE, UW, Ub, watoms, hB, N);

    // readout: y = (h4 + x) @ R_W + R_b, BN stats fused
    int yblocks = 512;
    int ychunk = (N + yblocks - 1) / yblocks;
    k_y<<<yblocks, 256, 0, stream>>>(hB, x, RW, Rb, ybuf, colstat, colstat + RD, N, ychunk);
    k_gbounds<<<(N + 256) / 256, 256, 0, stream>>>(batch, gstart, N, G);
    k_out<<<G, RD, 0, stream>>>(ybuf, colstat, colstat + RD, Rg, Rbe, gstart, out, 1.0f / (float)N);
}

// Round 21
// 612.729 us; speedup vs baseline: 1.2234x; 1.2234x over previous
//
#include <hip/hip_runtime.h>
#include <hip/hip_fp16.h>
#include <cstdint>
#include <cstddef>

#define NODE 64
#define EDGEF 32
#define UPF 160   // 2*NODE + EDGEF
#define RD 256
#define UT_STRIDE 162  // 160 padded: float2 reads -> 2-way bank aliasing (free)

typedef unsigned int uint4n __attribute__((ext_vector_type(4)));  // native vec for nt-store

__device__ __forceinline__ float eluf(float x) { return x > 0.f ? x : expm1f(x); }

union U32H2 { unsigned int u; __half2 h; };
union H16U { __half h; unsigned short u; };

__device__ __forceinline__ float2 h2f(unsigned int u) {
    U32H2 t; t.u = u;
    return __half22float2(t.h);
}
__device__ __forceinline__ unsigned short f2h(float f) {
    H16U t; t.h = __float2half_rn(f);
    return t.u;
}

// ---------------------------------------------------------------------------
// CSR build. k_count also records each edge's rank within its dst segment
// (the atomic's return value) so the fill pass needs NO second atomic.
__global__ void k_count(const int* __restrict__ dst, int* cnt, int* rank, int E) {
    int e = blockIdx.x * 256 + threadIdx.x;
    if (e < E) rank[e] = atomicAdd(&cnt[dst[e]], 1);
}

__global__ void k_scanA(const int* __restrict__ cnt, int* starts, int* bsum, int N) {
    __shared__ int sh[256];
    int t = threadIdx.x;
    int base = blockIdx.x * 1024 + t * 4;
    int v0 = 0, v1 = 0, v2 = 0, v3 = 0;
    if (base + 0 < N) v0 = cnt[base + 0];
    if (base + 1 < N) v1 = cnt[base + 1];
    if (base + 2 < N) v2 = cnt[base + 2];
    if (base + 3 < N) v3 = cnt[base + 3];
    int tot = v0 + v1 + v2 + v3;
    sh[t] = tot;
    __syncthreads();
    for (int off = 1; off < 256; off <<= 1) {
        int add = (t >= off) ? sh[t - off] : 0;
        __syncthreads();
        sh[t] += add;
        __syncthreads();
    }
    int excl = sh[t] - tot;
    if (base + 0 < N) starts[base + 0] = excl;
    if (base + 1 < N) starts[base + 1] = excl + v0;
    if (base + 2 < N) starts[base + 2] = excl + v0 + v1;
    if (base + 3 < N) starts[base + 3] = excl + v0 + v1 + v2;
    if (t == 255) bsum[blockIdx.x] = sh[255];
}

__global__ void k_scanB(const int* __restrict__ bsum, int* boff, int nb, int* starts, int N) {
    if (threadIdx.x == 0 && blockIdx.x == 0) {
        int run = 0;
        for (int b = 0; b < nb; ++b) { boff[b] = run; run += bsum[b]; }
        starts[N] = run;
    }
}

__global__ void k_scanC(const int* __restrict__ boff, int* starts, int N) {
    int i = blockIdx.x * 256 + threadIdx.x;
    if (i < N) starts[i] += boff[i >> 10];
}

// ---------------------------------------------------------------------------
// Tiny id-scatter: pos = starts[dst] + rank; one 16B nontemporal store.
__global__ void k_fill_ids(const int* __restrict__ src, const int* __restrict__ dst,
                           const float* __restrict__ wb, const int* __restrict__ rank,
                           const int* __restrict__ starts, uint4n* __restrict__ ecsr, int E) {
    int e = blockIdx.x * 256 + threadIdx.x;
    if (e >= E) return;
    int pos = starts[dst[e]] + rank[e];
    uint4n rec;
    rec.x = (unsigned int)src[e];
    rec.y = __float_as_uint(wb[e]);
    rec.z = (unsigned int)e;
    rec.w = 0u;
    __builtin_nontemporal_store(rec, &ecsr[pos]);
}

// ---------------------------------------------------------------------------
// Edge FFN, 8-lane-group per edge (register-light; round-17: FETCH 310->52MB,
// round-18: NO min-waves bound or it spills).
__global__ __launch_bounds__(256) void k_medge(
    const float* __restrict__ ea, const float* __restrict__ wb,
    const float* __restrict__ EW, const float* __restrict__ Eb,
    unsigned short* __restrict__ medge, int E) {
    __shared__ float ew_s[EDGEF * EDGEF];
    __shared__ float eb_s[EDGEF];
    int tid = threadIdx.x;
    for (int i = tid; i < EDGEF * EDGEF; i += 256) ew_s[i] = EW[i];
    if (tid < EDGEF) eb_s[tid] = Eb[tid];
    __syncthreads();
    int lane = tid & 63, wid = tid >> 6;
    int grp = lane >> 3, gl = lane & 7;
    const float4* ea4 = (const float4*)ea;
    float4 eb4 = *(const float4*)&eb_s[gl * 4];
    for (int e0 = blockIdx.x * 32; e0 < E; e0 += gridDim.x * 32) {
        int e = e0 + wid * 8 + grp;
        float4 a4 = {0.f, 0.f, 0.f, 0.f};
        float w = 0.f;
        if (e < E) {
            a4 = ea4[(size_t)e * 8 + gl];
            w = wb[e];
        }
        float4 m = eb4;
#pragma unroll
        for (int k = 0; k < EDGEF; ++k) {
            float av;
            switch (k & 3) {
                case 0: av = a4.x; break;
                case 1: av = a4.y; break;
                case 2: av = a4.z; break;
                default: av = a4.w; break;
            }
            float ak = __shfl(av, (lane & 56) | (k >> 2), 64);
            float4 w4 = *(const float4*)&ew_s[k * EDGEF + gl * 4];
            m.x = fmaf(ak, w4.x, m.x);
            m.y = fmaf(ak, w4.y, m.y);
            m.z = fmaf(ak, w4.z, m.z);
            m.w = fmaf(ak, w4.w, m.w);
        }
        if (e < E) {
            uint2 o;
            o.x = (unsigned int)f2h(w * fmaxf(m.x, 0.f)) |
                  ((unsigned int)f2h(w * fmaxf(m.y, 0.f)) << 16);
            o.y = (unsigned int)f2h(w * fmaxf(m.z, 0.f)) |
                  ((unsigned int)f2h(w * fmaxf(m.w, 0.f)) << 16);
            *(uint2*)(medge + (size_t)e * EDGEF + gl * 4) = o;
        }
    }
}

// ---------------------------------------------------------------------------
// Segment-sum via gather: aggrE[n] = elu( sum_i medge[ecsr[i].z] ).
__global__ __launch_bounds__(256) void k_sumE(
    const unsigned short* __restrict__ medge, const uint4n* __restrict__ ecsr,
    const int* __restrict__ starts, float* __restrict__ aggrE_elu, int N) {
    int tid = threadIdx.x;
    int lane = tid & 63, wid = tid >> 6;
    int grp = lane >> 2, gl = lane & 3;      // 16 groups x 4 lanes
    int nwaves = gridDim.x * 4;
    for (int n = blockIdx.x * 4 + wid; n < N; n += nwaves) {
        int s0 = starts[n], s1 = starts[n + 1];
        float acc[8] = {0.f, 0.f, 0.f, 0.f, 0.f, 0.f, 0.f, 0.f};
        int i = s0 + grp;
        uint4 r0 = {0u,0u,0u,0u}, r1 = {0u,0u,0u,0u};
        if (i < s1)      r0 = *(const uint4*)(medge + (size_t)ecsr[i].z      * EDGEF + gl * 8);
        if (i + 16 < s1) r1 = *(const uint4*)(medge + (size_t)ecsr[i + 16].z * EDGEF + gl * 8);
        for (; i < s1; i += 16) {
            uint4 rN = {0u,0u,0u,0u};
            if (i + 32 < s1) rN = *(const uint4*)(medge + (size_t)ecsr[i + 32].z * EDGEF + gl * 8);
            float2 f0 = h2f(r0.x), f1 = h2f(r0.y), f2 = h2f(r0.z), f3 = h2f(r0.w);
            acc[0] += f0.x; acc[1] += f0.y;
            acc[2] += f1.x; acc[3] += f1.y;
            acc[4] += f2.x; acc[5] += f2.y;
            acc[6] += f3.x; acc[7] += f3.y;
            r0 = r1; r1 = rN;
        }
#pragma unroll
        for (int m2 = 4; m2 <= 32; m2 <<= 1) {
#pragma unroll
            for (int j = 0; j < 8; ++j) acc[j] += __shfl_xor(acc[j], m2, 64);
        }
        if (lane < 4) {
            float4 o0 = { eluf(acc[0]), eluf(acc[1]), eluf(acc[2]), eluf(acc[3]) };
            float4 o1 = { eluf(acc[4]), eluf(acc[5]), eluf(acc[6]), eluf(acc[7]) };
            float4* op = (float4*)(aggrE_elu + (size_t)n * EDGEF + gl * 8);
            op[0] = o0;
            op[1] = o1;
        }
    }
}

// ---------------------------------------------------------------------------
// hv = relu((ha [+ hb]) @ V_W + V_b), stored as fp16 (halves gather bytes).
__global__ __launch_bounds__(256) void k_hv(
    const float* __restrict__ ha, const float* __restrict__ hb, int addB,
    const float* __restrict__ VW, const float* __restrict__ Vb,
    unsigned short* __restrict__ hvh, int N, int chunk) {
    __shared__ float slot[4][NODE];
    int tid = threadIdx.x;
    int lane = tid & 63, w = tid >> 6;
    float vcol[NODE];
#pragma unroll
    for (int k = 0; k < NODE; ++k) vcol[k] = VW[k * NODE + lane];
    float vb = Vb[lane];
    const float4* s4 = (const float4*)slot[w];
    int n0 = blockIdx.x * chunk;
    int n1 = n0 + chunk; if (n1 > N) n1 = N;
    for (int n = n0 + w; n < n1; n += 4) {
        float hrow = ha[(size_t)n * NODE + lane];
        if (addB) hrow += hb[(size_t)n * NODE + lane];
        slot[w][lane] = hrow;
        float d0 = 0.f, d1 = 0.f, d2 = 0.f, d3 = 0.f;
#pragma unroll
        for (int q = 0; q < 16; ++q) {
            float4 h4 = s4[q];
            d0 = fmaf(h4.x, vcol[4*q+0], d0);
            d1 = fmaf(h4.y, vcol[4*q+1], d1);
            d2 = fmaf(h4.z, vcol[4*q+2], d2);
            d3 = fmaf(h4.w, vcol[4*q+3], d3);
        }
        hvh[(size_t)n * NODE + lane] = f2h(fmaxf(vb + ((d0 + d1) + (d2 + d3)), 0.f));
    }
}

// ---------------------------------------------------------------------------
// Pure gather (fp16 rows): aggr[n] = sum_e w_e * hv[src_e]. 8-lane groups
// (uint4 = 8 halves/lane, row = 8 lanes x 16B): 8 edges concurrent per wave
// x 3-deep ring = 24 rows in flight; src+w come from one uint4 ecsr read.
__global__ __launch_bounds__(512, 8) void k_gather(
    const unsigned short* __restrict__ hvh, const int* __restrict__ starts,
    const uint4n* __restrict__ ecsr, float* __restrict__ aggr, int N) {
    int lane = threadIdx.x & 63, wid = threadIdx.x >> 6;
    int grp = lane >> 3, gl = lane & 7;      // 8 groups x 8 lanes
    int nwaves = gridDim.x * 8;
    for (int n = blockIdx.x * 8 + wid; n < N; n += nwaves) {
        int s0 = starts[n], s1 = starts[n + 1];
        int deg = s1 - s0;
        float acc[8] = {0.f, 0.f, 0.f, 0.f, 0.f, 0.f, 0.f, 0.f};
        uint4 r0 = {0u,0u,0u,0u}, r1 = {0u,0u,0u,0u}, r2 = {0u,0u,0u,0u};
        float w0 = 0.f, w1 = 0.f, w2 = 0.f;
        if (grp < deg) {
            uint4n c = ecsr[s0 + grp];
            r0 = *(const uint4*)(hvh + (size_t)c.x * NODE + gl * 8);
            w0 = __uint_as_float(c.y);
        }
        if (grp + 8 < deg) {
            uint4n c = ecsr[s0 + grp + 8];
            r1 = *(const uint4*)(hvh + (size_t)c.x * NODE + gl * 8);
            w1 = __uint_as_float(c.y);
        }
        if (grp + 16 < deg) {
            uint4n c = ecsr[s0 + grp + 16];
            r2 = *(const uint4*)(hvh + (size_t)c.x * NODE + gl * 8);
            w2 = __uint_as_float(c.y);
        }
        for (int i = grp; i < deg; i += 8) {
            uint4 rN = {0u,0u,0u,0u}; float wN = 0.f;
            if (i + 24 < deg) {
                uint4n c = ecsr[s0 + i + 24];
                rN = *(const uint4*)(hvh + (size_t)c.x * NODE + gl * 8);
                wN = __uint_as_float(c.y);
            }
            float2 f0 = h2f(r0.x), f1 = h2f(r0.y), f2 = h2f(r0.z), f3 = h2f(r0.w);
            acc[0] = fmaf(w0, f0.x, acc[0]);
            acc[1] = fmaf(w0, f0.y, acc[1]);
            acc[2] = fmaf(w0, f1.x, acc[2]);
            acc[3] = fmaf(w0, f1.y, acc[3]);
            acc[4] = fmaf(w0, f2.x, acc[4]);
            acc[5] = fmaf(w0, f2.y, acc[5]);
            acc[6] = fmaf(w0, f3.x, acc[6]);
            acc[7] = fmaf(w0, f3.y, acc[7]);
            r0 = r1; w0 = w1;
            r1 = r2; w1 = w2;
            r2 = rN; w2 = wN;
        }
        // reduce across the 8 groups (lane bits 3..5)
#pragma unroll
        for (int m2 = 8; m2 <= 32; m2 <<= 1) {
#pragma unroll
            for (int j = 0; j < 8; ++j) acc[j] += __shfl_xor(acc[j], m2, 64);
        }
        if (lane < 8) {
            float4* op = (float4*)(aggr + (size_t)n * NODE + gl * 8);
            float4 o0 = { acc[0], acc[1], acc[2], acc[3] };
            float4 o1 = { acc[4], acc[5], acc[6], acc[7] };
            op[0] = o0;
            op[1] = o1;
        }
    }
}

// ---------------------------------------------------------------------------
// Dense node update: up = elu([aggr | aggrE | h_n]) -> U-FFN -> h_out.
__global__ __launch_bounds__(512, 4) void k_update(
    const float* __restrict__ ha, const float* __restrict__ hb, int addB,
    const float* __restrict__ aggr, const float* __restrict__ aggrE_elu,
    const float* __restrict__ UW, const float* __restrict__ Ub,
    const float* __restrict__ watoms, float* __restrict__ h_out, int N) {
    __shared__ float lds_Ut[NODE * UT_STRIDE];   // 41.4 KB
    __shared__ float lds_up[8 * UPF];            // 5 KB
    int tid = threadIdx.x;
    for (int idx = tid; idx < UPF * NODE; idx += 512) {
        int j = idx & 63, t2 = idx >> 6;
        lds_Ut[j * UT_STRIDE + t2] = UW[idx];
    }
    int lane = tid & 63, wid = tid >> 6;
    float ub = Ub[lane];
    __syncthreads();
    float* myup = lds_up + wid * UPF;
    int nwaves = gridDim.x * 8;
    for (int n = blockIdx.x * 8 + wid; n < N; n += nwaves) {
        myup[lane] = eluf(aggr[(size_t)n * NODE + lane]);
        if (lane < EDGEF) myup[NODE + lane] = aggrE_elu[(size_t)n * EDGEF + lane];
        float hrow = ha[(size_t)n * NODE + lane];
        if (addB) hrow += hb[(size_t)n * NODE + lane];
        myup[NODE + EDGEF + lane] = eluf(hrow);
        float o = ub;
#pragma unroll
        for (int t2 = 0; t2 < UPF; t2 += 2) {
            float2 u2 = *(const float2*)&myup[t2];                 // broadcast
            float2 w2 = *(const float2*)&lds_Ut[lane * UT_STRIDE + t2];
            o = fmaf(u2.x, w2.x, o);
            o = fmaf(u2.y, w2.y, o);
        }
        h_out[(size_t)n * NODE + lane] = fmaxf(o, 0.f) * watoms[n];
    }
}

// ---------------------------------------------------------------------------
// Readout GEMM y = (ha+hb) @ R_W + R_b, fused BN column stats.
// 512 blocks (measured best: 512->71us, 2048->78us, round-19).
__global__ __launch_bounds__(256) void k_y(
    const float* __restrict__ ha, const float* __restrict__ hb,
    const float* __restrict__ RW, const float* __restrict__ Rb,
    float* __restrict__ y, float* colsum, float* colsumsq, int N, int chunk) {
    __shared__ float slot[4][NODE];
    int tid = threadIdx.x;
    int lane = tid & 63, w = tid >> 6;
    float rcol[NODE];
#pragma unroll
    for (int k = 0; k < NODE; ++k) rcol[k] = RW[k * RD + w * 64 + lane];
    float rb = Rb[w * 64 + lane];
    const float4* s4 = (const float4*)slot[w];
    float sum = 0.f, sq = 0.f;
    int n0 = blockIdx.x * chunk;
    int n1 = n0 + chunk; if (n1 > N) n1 = N;
    for (int n = n0; n < n1; ++n) {
        float hvC = ha[(size_t)n * NODE + lane] + hb[(size_t)n * NODE + lane];
        slot[w][lane] = hvC;
        float d0 = 0.f, d1 = 0.f, d2 = 0.f, d3 = 0.f;
#pragma unroll
        for (int q = 0; q < 16; ++q) {
            float4 h4 = s4[q];
            d0 = fmaf(h4.x, rcol[4*q+0], d0);
            d1 = fmaf(h4.y, rcol[4*q+1], d1);
            d2 = fmaf(h4.z, rcol[4*q+2], d2);
            d3 = fmaf(h4.w, rcol[4*q+3], d3);
        }
        float v = rb + ((d0 + d1) + (d2 + d3));
        y[(size_t)n * RD + w * 64 + lane] = v;
        sum += v; sq = fmaf(v, v, sq);
    }
    atomicAdd(&colsum[w * 64 + lane], sum);
    atomicAdd(&colsumsq[w * 64 + lane], sq);
}

// graph boundaries from sorted batch: gstart[g] = first n with batch[n] >= g
__global__ void k_gbounds(const int* __restrict__ batch, int* gstart, int N, int G) {
    int n = blockIdx.x * 256 + threadIdx.x;
    if (n > N) return;
    int bprev = (n == 0) ? -1 : batch[n - 1];
    int bcur = (n == N) ? G : batch[n];
    for (int g = bprev + 1; g <= bcur; ++g) gstart[g] = n;
}

// BN(normalize) + relu + segment mean. block per graph, thread per channel.
__global__ void k_out(const float* __restrict__ y, const float* __restrict__ colsum,
                      const float* __restrict__ colsumsq, const float* __restrict__ gamma,
                      const float* __restrict__ beta, const int* __restrict__ gstart,
                      float* __restrict__ out, float invN) {
    int g = blockIdx.x, c = threadIdx.x;
    float mu = colsum[c] * invN;
    float var = fmaxf(colsumsq[c] * invN - mu * mu, 0.f);
    float inv = rsqrtf(var + 1e-5f);
    float ga = gamma[c], be = beta[c];
    int a = gstart[g], b = gstart[g + 1];
    float acc = 0.f;
    for (int n = a; n < b; ++n) {
        float v = y[(size_t)n * RD + c];
        acc += fmaxf(fmaf((v - mu) * inv, ga, be), 0.f);
    }
    out[(size_t)g * RD + c] = acc / fmaxf((float)(b - a), 1.f);
}

// ---------------------------------------------------------------------------
extern "C" void kernel_launch(void* const* d_in, const int* in_sizes, int n_in,
                              void* d_out, int out_size, void* d_ws, size_t ws_size,
                              hipStream_t stream) {
    const float* x      = (const float*)d_in[0];
    const int*   ei     = (const int*)d_in[1];
    const float* eattr  = (const float*)d_in[2];
    const float* watoms = (const float*)d_in[3];
    const float* wbonds = (const float*)d_in[4];
    const int*   batch  = (const int*)d_in[5];
    const float* VW = (const float*)d_in[6];
    const float* Vb = (const float*)d_in[7];
    const float* EW = (const float*)d_in[8];
    const float* Eb = (const float*)d_in[9];
    const float* UW = (const float*)d_in[10];
    const float* Ub = (const float*)d_in[11];
    const float* RW = (const float*)d_in[12];
    const float* Rb = (const float*)d_in[13];
    const float* Rg = (const float*)d_in[14];
    const float* Rbe = (const float*)d_in[15];
    float* out = (float*)d_out;

    const int N = in_sizes[0] / NODE;
    const int E = in_sizes[4];
    const int G = out_size / RD;
    const int* src = ei;
    const int* dst = ei + E;

    char* p = (char*)d_ws;
    auto alloc = [&](size_t bytes) -> char* {
        char* r = p;
        p += (bytes + 255) & ~(size_t)255;
        return r;
    };
    float* aggrE   = (float*)alloc((size_t)N * EDGEF * 4);   // stores elu(aggrE)
    int*   cnt     = (int*)alloc((size_t)N * 4);
    int*   starts  = (int*)alloc((size_t)(N + 1) * 4);
    int*   rank    = (int*)alloc((size_t)E * 4);
    int*   bsum    = (int*)alloc(64 * 4);
    int*   boff    = (int*)alloc(64 * 4);
    uint4n* ecsr   = (uint4n*)alloc((size_t)E * 16);         // (src, w, e, 0) per CSR slot
    float* hA      = (float*)alloc((size_t)N * NODE * 4);    // h1, then h3 (in place)
    float* hB      = (float*)alloc((size_t)N * NODE * 4);    // h2, then h4 (in place)
    unsigned short* hvh = (unsigned short*)alloc((size_t)N * NODE * 2); // fp16 relu(V h)
    float* aggr    = (float*)alloc((size_t)N * NODE * 4);    // gathered node messages
    float* colstat = (float*)alloc((size_t)2 * RD * 4);
    int*   gstart  = (int*)alloc((size_t)(G + 1) * 4);
    // medge (E*32 fp16 = 51.2MB) and ybuf (N*256 f32 = 51.2MB): disjoint
    // lifetimes -> overlay.
    size_t mbytes = (size_t)E * EDGEF * 2;
    size_t ybytes = (size_t)N * RD * 4;
    float* ybuf = (float*)alloc(mbytes > ybytes ? mbytes : ybytes);
    unsigned short* medge = (unsigned short*)ybuf;

    hipMemsetAsync(cnt, 0, (size_t)N * 4, stream);
    hipMemsetAsync(colstat, 0, (size_t)2 * RD * 4, stream);

    int eblocks = (E + 255) / 256;
    int sblocks = (N + 1023) / 1024;

    k_count<<<eblocks, 256, 0, stream>>>(dst, cnt, rank, E);
    k_scanA<<<sblocks, 256, 0, stream>>>(cnt, starts, bsum, N);
    k_scanB<<<1, 64, 0, stream>>>(bsum, boff, sblocks, starts, N);
    k_scanC<<<(N + 255) / 256, 256, 0, stream>>>(boff, starts, N);
    k_fill_ids<<<eblocks, 256, 0, stream>>>(src, dst, wbonds, rank, starts, ecsr, E);
    k_medge<<<2048, 256, 0, stream>>>(eattr, wbonds, EW, Eb, medge, E);
    k_sumE<<<2048, 256, 0, stream>>>(medge, ecsr, starts, aggrE, N);

    int hvblocks = 512;
    int chunk = (N + hvblocks - 1) / hvblocks;

    // depth 0: h1 = mp(x)
    k_hv<<<hvblocks, 256, 0, stream>>>(x, x, 0, VW, Vb, hvh, N, chunk);
    k_gather<<<2048, 512, 0, stream>>>(hvh, starts, ecsr, aggr, N);
    k_update<<<768, 512, 0, stream>>>(x, x, 0, aggr, aggrE, UW, Ub, watoms, hA, N);
    // depth 1: h2 = mp(h1)
    k_hv<<<hvblocks, 256, 0, stream>>>(hA, hA, 0, VW, Vb, hvh, N, chunk);
    k_gather<<<2048, 512, 0, stream>>>(hvh, starts, ecsr, aggr, N);
    k_update<<<768, 512, 0, stream>>>(hA, hA, 0, aggr, aggrE, UW, Ub, watoms, hB, N);
    // depth 2: h3 = mp(h1 + h2)   (in place into hA)
    k_hv<<<hvblocks, 256, 0, stream>>>(hA, hB, 1, VW, Vb, hvh, N, chunk);
    k_gather<<<2048, 512, 0, stream>>>(hvh, starts, ecsr, aggr, N);
    k_update<<<768, 512, 0, stream>>>(hA, hB, 1, aggr, aggrE, UW, Ub, watoms, hA, N);
    // depth 3: h4 = mp(h2 + h3)   (in place into hB)
    k_hv<<<hvblocks, 256, 0, stream>>>(hB, hA, 1, VW, Vb, hvh, N, chunk);
    k_gather<<<2048, 512, 0, stream>>>(hvh, starts, ecsr, aggr, N);
    k_update<<<768, 512, 0, stream>>>(hB, hA, 1, aggr, aggrE, UW, Ub, watoms, hB, N);

    // readout: y = (h4 + x) @ R_W + R_b, BN stats fused
    int yblocks = 512;
    int ychunk = (N + yblocks - 1) / yblocks;
    k_y<<<yblocks, 256, 0, stream>>>(hB, x, RW, Rb, ybuf, colstat, colstat + RD, N, ychunk);
    k_gbounds<<<(N + 256) / 256, 256, 0, stream>>>(batch, gstart, N, G);
    k_out<<<G, RD, 0, stream>>>(ybuf, colstat, colstat + RD, Rg, Rbe, gstart, out, 1.0f / (float)N);
}

// Round 22
// 601.880 us; speedup vs baseline: 1.2455x; 1.0180x over previous
//
#include <hip/hip_runtime.h>
#include <hip/hip_fp16.h>
#include <cstdint>
#include <cstddef>

#define NODE 64
#define EDGEF 32
#define UPF 160   // 2*NODE + EDGEF
#define RD 256
#define UT_STRIDE 162  // 160 padded: float2 reads -> 2-way bank aliasing (free)

typedef unsigned int uint4n __attribute__((ext_vector_type(4)));  // native vec for nt-store

__device__ __forceinline__ float eluf(float x) { return x > 0.f ? x : expm1f(x); }

union U32H2 { unsigned int u; __half2 h; };
union H16U { __half h; unsigned short u; };

__device__ __forceinline__ float2 h2f(unsigned int u) {
    U32H2 t; t.u = u;
    return __half22float2(t.h);
}
__device__ __forceinline__ unsigned short f2h(float f) {
    H16U t; t.h = __float2half_rn(f);
    return t.u;
}

// ---------------------------------------------------------------------------
// CSR build. k_count also records each edge's rank within its dst segment
// (the atomic's return value) so the fill pass needs NO second atomic.
__global__ void k_count(const int* __restrict__ dst, int* cnt, int* rank, int E) {
    int e = blockIdx.x * 256 + threadIdx.x;
    if (e < E) rank[e] = atomicAdd(&cnt[dst[e]], 1);
}

__global__ void k_scanA(const int* __restrict__ cnt, int* starts, int* bsum, int N) {
    __shared__ int sh[256];
    int t = threadIdx.x;
    int base = blockIdx.x * 1024 + t * 4;
    int v0 = 0, v1 = 0, v2 = 0, v3 = 0;
    if (base + 0 < N) v0 = cnt[base + 0];
    if (base + 1 < N) v1 = cnt[base + 1];
    if (base + 2 < N) v2 = cnt[base + 2];
    if (base + 3 < N) v3 = cnt[base + 3];
    int tot = v0 + v1 + v2 + v3;
    sh[t] = tot;
    __syncthreads();
    for (int off = 1; off < 256; off <<= 1) {
        int add = (t >= off) ? sh[t - off] : 0;
        __syncthreads();
        sh[t] += add;
        __syncthreads();
    }
    int excl = sh[t] - tot;
    if (base + 0 < N) starts[base + 0] = excl;
    if (base + 1 < N) starts[base + 1] = excl + v0;
    if (base + 2 < N) starts[base + 2] = excl + v0 + v1;
    if (base + 3 < N) starts[base + 3] = excl + v0 + v1 + v2;
    if (t == 255) bsum[blockIdx.x] = sh[255];
}

__global__ void k_scanB(const int* __restrict__ bsum, int* boff, int nb, int* starts, int N) {
    if (threadIdx.x == 0 && blockIdx.x == 0) {
        int run = 0;
        for (int b = 0; b < nb; ++b) { boff[b] = run; run += bsum[b]; }
        starts[N] = run;
    }
}

__global__ void k_scanC(const int* __restrict__ boff, int* starts, int N) {
    int i = blockIdx.x * 256 + threadIdx.x;
    if (i < N) starts[i] += boff[i >> 10];
}

// ---------------------------------------------------------------------------
// Tiny id-scatter: pos = starts[dst] + rank; one 16B nontemporal store.
__global__ void k_fill_ids(const int* __restrict__ src, const int* __restrict__ dst,
                           const float* __restrict__ wb, const int* __restrict__ rank,
                           const int* __restrict__ starts, uint4n* __restrict__ ecsr, int E) {
    int e = blockIdx.x * 256 + threadIdx.x;
    if (e >= E) return;
    int pos = starts[dst[e]] + rank[e];
    uint4n rec;
    rec.x = (unsigned int)src[e];
    rec.y = __float_as_uint(wb[e]);
    rec.z = (unsigned int)e;
    rec.w = 0u;
    __builtin_nontemporal_store(rec, &ecsr[pos]);
}

// ---------------------------------------------------------------------------
// Edge FFN, 8-lane-group per edge (register-light; round-17: FETCH 310->52MB,
// round-18: NO min-waves bound or it spills).
__global__ __launch_bounds__(256) void k_medge(
    const float* __restrict__ ea, const float* __restrict__ wb,
    const float* __restrict__ EW, const float* __restrict__ Eb,
    unsigned short* __restrict__ medge, int E) {
    __shared__ float ew_s[EDGEF * EDGEF];
    __shared__ float eb_s[EDGEF];
    int tid = threadIdx.x;
    for (int i = tid; i < EDGEF * EDGEF; i += 256) ew_s[i] = EW[i];
    if (tid < EDGEF) eb_s[tid] = Eb[tid];
    __syncthreads();
    int lane = tid & 63, wid = tid >> 6;
    int grp = lane >> 3, gl = lane & 7;
    const float4* ea4 = (const float4*)ea;
    float4 eb4 = *(const float4*)&eb_s[gl * 4];
    for (int e0 = blockIdx.x * 32; e0 < E; e0 += gridDim.x * 32) {
        int e = e0 + wid * 8 + grp;
        float4 a4 = {0.f, 0.f, 0.f, 0.f};
        float w = 0.f;
        if (e < E) {
            a4 = ea4[(size_t)e * 8 + gl];
            w = wb[e];
        }
        float4 m = eb4;
#pragma unroll
        for (int k = 0; k < EDGEF; ++k) {
            float av;
            switch (k & 3) {
                case 0: av = a4.x; break;
                case 1: av = a4.y; break;
                case 2: av = a4.z; break;
                default: av = a4.w; break;
            }
            float ak = __shfl(av, (lane & 56) | (k >> 2), 64);
            float4 w4 = *(const float4*)&ew_s[k * EDGEF + gl * 4];
            m.x = fmaf(ak, w4.x, m.x);
            m.y = fmaf(ak, w4.y, m.y);
            m.z = fmaf(ak, w4.z, m.z);
            m.w = fmaf(ak, w4.w, m.w);
        }
        if (e < E) {
            uint2 o;
            o.x = (unsigned int)f2h(w * fmaxf(m.x, 0.f)) |
                  ((unsigned int)f2h(w * fmaxf(m.y, 0.f)) << 16);
            o.y = (unsigned int)f2h(w * fmaxf(m.z, 0.f)) |
                  ((unsigned int)f2h(w * fmaxf(m.w, 0.f)) << 16);
            *(uint2*)(medge + (size_t)e * EDGEF + gl * 4) = o;
        }
    }
}

// ---------------------------------------------------------------------------
// Segment-sum via gather: aggrE[n] = elu( sum_i medge[ecsr[i].z] ).
__global__ __launch_bounds__(256) void k_sumE(
    const unsigned short* __restrict__ medge, const uint4n* __restrict__ ecsr,
    const int* __restrict__ starts, float* __restrict__ aggrE_elu, int N) {
    int tid = threadIdx.x;
    int lane = tid & 63, wid = tid >> 6;
    int grp = lane >> 2, gl = lane & 3;      // 16 groups x 4 lanes
    int nwaves = gridDim.x * 4;
    for (int n = blockIdx.x * 4 + wid; n < N; n += nwaves) {
        int s0 = starts[n], s1 = starts[n + 1];
        float acc[8] = {0.f, 0.f, 0.f, 0.f, 0.f, 0.f, 0.f, 0.f};
        int i = s0 + grp;
        uint4 r0 = {0u,0u,0u,0u}, r1 = {0u,0u,0u,0u};
        if (i < s1)      r0 = *(const uint4*)(medge + (size_t)ecsr[i].z      * EDGEF + gl * 8);
        if (i + 16 < s1) r1 = *(const uint4*)(medge + (size_t)ecsr[i + 16].z * EDGEF + gl * 8);
        for (; i < s1; i += 16) {
            uint4 rN = {0u,0u,0u,0u};
            if (i + 32 < s1) rN = *(const uint4*)(medge + (size_t)ecsr[i + 32].z * EDGEF + gl * 8);
            float2 f0 = h2f(r0.x), f1 = h2f(r0.y), f2 = h2f(r0.z), f3 = h2f(r0.w);
            acc[0] += f0.x; acc[1] += f0.y;
            acc[2] += f1.x; acc[3] += f1.y;
            acc[4] += f2.x; acc[5] += f2.y;
            acc[6] += f3.x; acc[7] += f3.y;
            r0 = r1; r1 = rN;
        }
#pragma unroll
        for (int m2 = 4; m2 <= 32; m2 <<= 1) {
#pragma unroll
            for (int j = 0; j < 8; ++j) acc[j] += __shfl_xor(acc[j], m2, 64);
        }
        if (lane < 4) {
            float4 o0 = { eluf(acc[0]), eluf(acc[1]), eluf(acc[2]), eluf(acc[3]) };
            float4 o1 = { eluf(acc[4]), eluf(acc[5]), eluf(acc[6]), eluf(acc[7]) };
            float4* op = (float4*)(aggrE_elu + (size_t)n * EDGEF + gl * 8);
            op[0] = o0;
            op[1] = o1;
        }
    }
}

// ---------------------------------------------------------------------------
// hv = relu((ha [+ hb]) @ V_W + V_b), stored as fp16 (halves gather bytes).
__global__ __launch_bounds__(256) void k_hv(
    const float* __restrict__ ha, const float* __restrict__ hb, int addB,
    const float* __restrict__ VW, const float* __restrict__ Vb,
    unsigned short* __restrict__ hvh, int N, int chunk) {
    __shared__ float slot[4][NODE];
    int tid = threadIdx.x;
    int lane = tid & 63, w = tid >> 6;
    float vcol[NODE];
#pragma unroll
    for (int k = 0; k < NODE; ++k) vcol[k] = VW[k * NODE + lane];
    float vb = Vb[lane];
    const float4* s4 = (const float4*)slot[w];
    int n0 = blockIdx.x * chunk;
    int n1 = n0 + chunk; if (n1 > N) n1 = N;
    for (int n = n0 + w; n < n1; n += 4) {
        float hrow = ha[(size_t)n * NODE + lane];
        if (addB) hrow += hb[(size_t)n * NODE + lane];
        slot[w][lane] = hrow;
        float d0 = 0.f, d1 = 0.f, d2 = 0.f, d3 = 0.f;
#pragma unroll
        for (int q = 0; q < 16; ++q) {
            float4 h4 = s4[q];
            d0 = fmaf(h4.x, vcol[4*q+0], d0);
            d1 = fmaf(h4.y, vcol[4*q+1], d1);
            d2 = fmaf(h4.z, vcol[4*q+2], d2);
            d3 = fmaf(h4.w, vcol[4*q+3], d3);
        }
        hvh[(size_t)n * NODE + lane] = f2h(fmaxf(vb + ((d0 + d1) + (d2 + d3)), 0.f));
    }
}

// ---------------------------------------------------------------------------
// Pure gather (fp16 rows): aggr[n] = sum_e w_e * hv[src_e]. 8-lane groups
// (uint4 = 8 halves/lane, row = 8 lanes x 16B): 8 edges concurrent per wave
// x 3-deep ring = 24 rows in flight; src+w come from one uint4 ecsr read.
__global__ __launch_bounds__(512, 8) void k_gather(
    const unsigned short* __restrict__ hvh, const int* __restrict__ starts,
    const uint4n* __restrict__ ecsr, float* __restrict__ aggr, int N) {
    int lane = threadIdx.x & 63, wid = threadIdx.x >> 6;
    int grp = lane >> 3, gl = lane & 7;      // 8 groups x 8 lanes
    int nwaves = gridDim.x * 8;
    for (int n = blockIdx.x * 8 + wid; n < N; n += nwaves) {
        int s0 = starts[n], s1 = starts[n + 1];
        int deg = s1 - s0;
        float acc[8] = {0.f, 0.f, 0.f, 0.f, 0.f, 0.f, 0.f, 0.f};
        uint4 r0 = {0u,0u,0u,0u}, r1 = {0u,0u,0u,0u}, r2 = {0u,0u,0u,0u};
        float w0 = 0.f, w1 = 0.f, w2 = 0.f;
        if (grp < deg) {
            uint4n c = ecsr[s0 + grp];
            r0 = *(const uint4*)(hvh + (size_t)c.x * NODE + gl * 8);
            w0 = __uint_as_float(c.y);
        }
        if (grp + 8 < deg) {
            uint4n c = ecsr[s0 + grp + 8];
            r1 = *(const uint4*)(hvh + (size_t)c.x * NODE + gl * 8);
            w1 = __uint_as_float(c.y);
        }
        if (grp + 16 < deg) {
            uint4n c = ecsr[s0 + grp + 16];
            r2 = *(const uint4*)(hvh + (size_t)c.x * NODE + gl * 8);
            w2 = __uint_as_float(c.y);
        }
        for (int i = grp; i < deg; i += 8) {
            uint4 rN = {0u,0u,0u,0u}; float wN = 0.f;
            if (i + 24 < deg) {
                uint4n c = ecsr[s0 + i + 24];
                rN = *(const uint4*)(hvh + (size_t)c.x * NODE + gl * 8);
                wN = __uint_as_float(c.y);
            }
            float2 f0 = h2f(r0.x), f1 = h2f(r0.y), f2 = h2f(r0.z), f3 = h2f(r0.w);
            acc[0] = fmaf(w0, f0.x, acc[0]);
            acc[1] = fmaf(w0, f0.y, acc[1]);
            acc[2] = fmaf(w0, f1.x, acc[2]);
            acc[3] = fmaf(w0, f1.y, acc[3]);
            acc[4] = fmaf(w0, f2.x, acc[4]);
            acc[5] = fmaf(w0, f2.y, acc[5]);
            acc[6] = fmaf(w0, f3.x, acc[6]);
            acc[7] = fmaf(w0, f3.y, acc[7]);
            r0 = r1; w0 = w1;
            r1 = r2; w1 = w2;
            r2 = rN; w2 = wN;
        }
        // reduce across the 8 groups (lane bits 3..5)
#pragma unroll
        for (int m2 = 8; m2 <= 32; m2 <<= 1) {
#pragma unroll
            for (int j = 0; j < 8; ++j) acc[j] += __shfl_xor(acc[j], m2, 64);
        }
        if (lane < 8) {
            float4* op = (float4*)(aggr + (size_t)n * NODE + gl * 8);
            float4 o0 = { acc[0], acc[1], acc[2], acc[3] };
            float4 o1 = { acc[4], acc[5], acc[6], acc[7] };
            op[0] = o0;
            op[1] = o1;
        }
    }
}

// ---------------------------------------------------------------------------
// Dense node update: up = elu([aggr | aggrE | h_n]) -> U-FFN -> h_out.
__global__ __launch_bounds__(512, 4) void k_update(
    const float* __restrict__ ha, const float* __restrict__ hb, int addB,
    const float* __restrict__ aggr, const float* __restrict__ aggrE_elu,
    const float* __restrict__ UW, const float* __restrict__ Ub,
    const float* __restrict__ watoms, float* __restrict__ h_out, int N) {
    __shared__ float lds_Ut[NODE * UT_STRIDE];   // 41.4 KB
    __shared__ float lds_up[8 * UPF];            // 5 KB
    int tid = threadIdx.x;
    for (int idx = tid; idx < UPF * NODE; idx += 512) {
        int j = idx & 63, t2 = idx >> 6;
        lds_Ut[j * UT_STRIDE + t2] = UW[idx];
    }
    int lane = tid & 63, wid = tid >> 6;
    float ub = Ub[lane];
    __syncthreads();
    float* myup = lds_up + wid * UPF;
    int nwaves = gridDim.x * 8;
    for (int n = blockIdx.x * 8 + wid; n < N; n += nwaves) {
        myup[lane] = eluf(aggr[(size_t)n * NODE + lane]);
        if (lane < EDGEF) myup[NODE + lane] = aggrE_elu[(size_t)n * EDGEF + lane];
        float hrow = ha[(size_t)n * NODE + lane];
        if (addB) hrow += hb[(size_t)n * NODE + lane];
        myup[NODE + EDGEF + lane] = eluf(hrow);
        float o = ub;
#pragma unroll
        for (int t2 = 0; t2 < UPF; t2 += 2) {
            float2 u2 = *(const float2*)&myup[t2];                 // broadcast
            float2 w2 = *(const float2*)&lds_Ut[lane * UT_STRIDE + t2];
            o = fmaf(u2.x, w2.x, o);
            o = fmaf(u2.y, w2.y, o);
        }
        h_out[(size_t)n * NODE + lane] = fmaxf(o, 0.f) * watoms[n];
    }
}

// ---------------------------------------------------------------------------
// Readout GEMM y = (ha+hb) @ R_W + R_b, fused BN column stats.
// 512 blocks (2048 re-fetches the R-columns per block: slower, round-19).
// One-node-ahead register prefetch hides the per-node global-load latency
// (dropped by accident in round 11; restored).
__global__ __launch_bounds__(256) void k_y(
    const float* __restrict__ ha, const float* __restrict__ hb,
    const float* __restrict__ RW, const float* __restrict__ Rb,
    float* __restrict__ y, float* colsum, float* colsumsq, int N, int chunk) {
    __shared__ float slot[4][NODE];
    int tid = threadIdx.x;
    int lane = tid & 63, w = tid >> 6;
    float rcol[NODE];
#pragma unroll
    for (int k = 0; k < NODE; ++k) rcol[k] = RW[k * RD + w * 64 + lane];
    float rb = Rb[w * 64 + lane];
    const float4* s4 = (const float4*)slot[w];
    float sum = 0.f, sq = 0.f;
    int n0 = blockIdx.x * chunk;
    int n1 = n0 + chunk; if (n1 > N) n1 = N;
    float aC = 0.f, bC = 0.f;
    if (n0 < n1) {
        aC = ha[(size_t)n0 * NODE + lane];
        bC = hb[(size_t)n0 * NODE + lane];
    }
    for (int n = n0; n < n1; ++n) {
        float aN = 0.f, bN = 0.f;
        if (n + 1 < n1) {
            aN = ha[(size_t)(n + 1) * NODE + lane];
            bN = hb[(size_t)(n + 1) * NODE + lane];
        }
        slot[w][lane] = aC + bC;
        float d0 = 0.f, d1 = 0.f, d2 = 0.f, d3 = 0.f;
#pragma unroll
        for (int q = 0; q < 16; ++q) {
            float4 h4 = s4[q];
            d0 = fmaf(h4.x, rcol[4*q+0], d0);
            d1 = fmaf(h4.y, rcol[4*q+1], d1);
            d2 = fmaf(h4.z, rcol[4*q+2], d2);
            d3 = fmaf(h4.w, rcol[4*q+3], d3);
        }
        float v = rb + ((d0 + d1) + (d2 + d3));
        y[(size_t)n * RD + w * 64 + lane] = v;
        sum += v; sq = fmaf(v, v, sq);
        aC = aN; bC = bN;
    }
    atomicAdd(&colsum[w * 64 + lane], sum);
    atomicAdd(&colsumsq[w * 64 + lane], sq);
}

// graph boundaries from sorted batch: gstart[g] = first n with batch[n] >= g
__global__ void k_gbounds(const int* __restrict__ batch, int* gstart, int N, int G) {
    int n = blockIdx.x * 256 + threadIdx.x;
    if (n > N) return;
    int bprev = (n == 0) ? -1 : batch[n - 1];
    int bcur = (n == N) ? G : batch[n];
    for (int g = bprev + 1; g <= bcur; ++g) gstart[g] = n;
}

// BN(normalize) + relu + segment mean. block per graph, thread per channel.
__global__ void k_out(const float* __restrict__ y, const float* __restrict__ colsum,
                      const float* __restrict__ colsumsq, const float* __restrict__ gamma,
                      const float* __restrict__ beta, const int* __restrict__ gstart,
                      float* __restrict__ out, float invN) {
    int g = blockIdx.x, c = threadIdx.x;
    float mu = colsum[c] * invN;
    float var = fmaxf(colsumsq[c] * invN - mu * mu, 0.f);
    float inv = rsqrtf(var + 1e-5f);
    float ga = gamma[c], be = beta[c];
    int a = gstart[g], b = gstart[g + 1];
    float acc = 0.f;
    for (int n = a; n < b; ++n) {
        float v = y[(size_t)n * RD + c];
        acc += fmaxf(fmaf((v - mu) * inv, ga, be), 0.f);
    }
    out[(size_t)g * RD + c] = acc / fmaxf((float)(b - a), 1.f);
}

// ---------------------------------------------------------------------------
extern "C" void kernel_launch(void* const* d_in, const int* in_sizes, int n_in,
                              void* d_out, int out_size, void* d_ws, size_t ws_size,
                              hipStream_t stream) {
    const float* x      = (const float*)d_in[0];
    const int*   ei     = (const int*)d_in[1];
    const float* eattr  = (const float*)d_in[2];
    const float* watoms = (const float*)d_in[3];
    const float* wbonds = (const float*)d_in[4];
    const int*   batch  = (const int*)d_in[5];
    const float* VW = (const float*)d_in[6];
    const float* Vb = (const float*)d_in[7];
    const float* EW = (const float*)d_in[8];
    const float* Eb = (const float*)d_in[9];
    const float* UW = (const float*)d_in[10];
    const float* Ub = (const float*)d_in[11];
    const float* RW = (const float*)d_in[12];
    const float* Rb = (const float*)d_in[13];
    const float* Rg = (const float*)d_in[14];
    const float* Rbe = (const float*)d_in[15];
    float* out = (float*)d_out;

    const int N = in_sizes[0] / NODE;
    const int E = in_sizes[4];
    const int G = out_size / RD;
    const int* src = ei;
    const int* dst = ei + E;

    char* p = (char*)d_ws;
    auto alloc = [&](size_t bytes) -> char* {
        char* r = p;
        p += (bytes + 255) & ~(size_t)255;
        return r;
    };
    float* aggrE   = (float*)alloc((size_t)N * EDGEF * 4);   // stores elu(aggrE)
    int*   cnt     = (int*)alloc((size_t)N * 4);
    int*   starts  = (int*)alloc((size_t)(N + 1) * 4);
    int*   rank    = (int*)alloc((size_t)E * 4);
    int*   bsum    = (int*)alloc(64 * 4);
    int*   boff    = (int*)alloc(64 * 4);
    uint4n* ecsr   = (uint4n*)alloc((size_t)E * 16);         // (src, w, e, 0) per CSR slot
    float* hA      = (float*)alloc((size_t)N * NODE * 4);    // h1, then h3 (in place)
    float* hB      = (float*)alloc((size_t)N * NODE * 4);    // h2, then h4 (in place)
    unsigned short* hvh = (unsigned short*)alloc((size_t)N * NODE * 2); // fp16 relu(V h)
    float* aggr    = (float*)alloc((size_t)N * NODE * 4);    // gathered node messages
    float* colstat = (float*)alloc((size_t)2 * RD * 4);
    int*   gstart  = (int*)alloc((size_t)(G + 1) * 4);
    // medge (E*32 fp16 = 51.2MB) and ybuf (N*256 f32 = 51.2MB): disjoint
    // lifetimes -> overlay.
    size_t mbytes = (size_t)E * EDGEF * 2;
    size_t ybytes = (size_t)N * RD * 4;
    float* ybuf = (float*)alloc(mbytes > ybytes ? mbytes : ybytes);
    unsigned short* medge = (unsigned short*)ybuf;

    hipMemsetAsync(cnt, 0, (size_t)N * 4, stream);
    hipMemsetAsync(colstat, 0, (size_t)2 * RD * 4, stream);

    int eblocks = (E + 255) / 256;
    int sblocks = (N + 1023) / 1024;

    k_count<<<eblocks, 256, 0, stream>>>(dst, cnt, rank, E);
    k_scanA<<<sblocks, 256, 0, stream>>>(cnt, starts, bsum, N);
    k_scanB<<<1, 64, 0, stream>>>(bsum, boff, sblocks, starts, N);
    k_scanC<<<(N + 255) / 256, 256, 0, stream>>>(boff, starts, N);
    k_fill_ids<<<eblocks, 256, 0, stream>>>(src, dst, wbonds, rank, starts, ecsr, E);
    k_medge<<<2048, 256, 0, stream>>>(eattr, wbonds, EW, Eb, medge, E);
    k_sumE<<<2048, 256, 0, stream>>>(medge, ecsr, starts, aggrE, N);

    int hvblocks = 512;
    int chunk = (N + hvblocks - 1) / hvblocks;

    // depth 0: h1 = mp(x)
    k_hv<<<hvblocks, 256, 0, stream>>>(x, x, 0, VW, Vb, hvh, N, chunk);
    k_gather<<<2048, 512, 0, stream>>>(hvh, starts, ecsr, aggr, N);
    k_update<<<768, 512, 0, stream>>>(x, x, 0, aggr, aggrE, UW, Ub, watoms, hA, N);
    // depth 1: h2 = mp(h1)
    k_hv<<<hvblocks, 256, 0, stream>>>(hA, hA, 0, VW, Vb, hvh, N, chunk);
    k_gather<<<2048, 512, 0, stream>>>(hvh, starts, ecsr, aggr, N);
    k_update<<<768, 512, 0, stream>>>(hA, hA, 0, aggr, aggrE, UW, Ub, watoms, hB, N);
    // depth 2: h3 = mp(h1 + h2)   (in place into hA)
    k_hv<<<hvblocks, 256, 0, stream>>>(hA, hB, 1, VW, Vb, hvh, N, chunk);
    k_gather<<<2048, 512, 0, stream>>>(hvh, starts, ecsr, aggr, N);
    k_update<<<768, 512, 0, stream>>>(hA, hB, 1, aggr, aggrE, UW, Ub, watoms, hA, N);
    // depth 3: h4 = mp(h2 + h3)   (in place into hB)
    k_hv<<<hvblocks, 256, 0, stream>>>(hB, hA, 1, VW, Vb, hvh, N, chunk);
    k_gather<<<2048, 512, 0, stream>>>(hvh, starts, ecsr, aggr, N);
    k_update<<<768, 512, 0, stream>>>(hB, hA, 1, aggr, aggrE, UW, Ub, watoms, hB, N);

    // readout: y = (h4 + x) @ R_W + R_b, BN stats fused
    int yblocks = 512;
    int ychunk = (N + yblocks - 1) / yblocks;
    k_y<<<yblocks, 256, 0, stream>>>(hB, x, RW, Rb, ybuf, colstat, colstat + RD, N, ychunk);
    k_gbounds<<<(N + 256) / 256, 256, 0, stream>>>(batch, gstart, N, G);
    k_out<<<G, RD, 0, stream>>>(ybuf, colstat, colstat + RD, Rg, Rbe, gstart, out, 1.0f / (float)N);
}